// Round 1
// baseline (742.153 us; speedup 1.0000x reference)
//
#include <hip/hip_runtime.h>
#include <math.h>

// StatisticalFeatureLoss: for k in {3,5,7}, depthwise gaussian-window local
// mean/var/skew/kurt of pred & target, scalar mean-abs-diff loss.
// Fully fused per window size: separable convs in LDS with 2r halo.

#define NTHREADS 256
#define TILE 32

static constexpr int H = 512;
static constexpr int W = 512;
static constexpr int PLANES = 48;      // 16 * 3
static constexpr float EPSF = 1e-8f;

__global__ void init_acc_kernel(double* acc) {
    if (threadIdx.x < 4) acc[threadIdx.x] = 0.0;
}

__global__ void final_kernel(const double* __restrict__ acc, float* __restrict__ out) {
    if (threadIdx.x == 0) {
        const double npix = (double)PLANES * H * W;   // 12582912
        double tot = acc[0] * 1.0 + acc[1] * 1.0 + acc[2] * 0.5 + acc[3] * 0.001;
        out[0] = (float)(tot / (npix * 12.0));
    }
}

template <int K>
__global__ __launch_bounds__(NTHREADS)
void stat_kernel(const float* __restrict__ pred, const float* __restrict__ targ,
                 double* __restrict__ acc) {
    constexpr int R   = K / 2;
    constexpr int SXS = TILE + 4 * R;     // x tile with double halo
    constexpr int SXP = SXS + 1;          // padded stride
    constexpr int SH  = TILE + 2 * R;     // h-field cols / mean dims
    constexpr int SHP = SH + 1;
    constexpr int SM  = TILE + 2 * R;
    constexpr int SMP = SM + 1;
    constexpr int TV  = TILE + 1;         // v-field stride

    __shared__ float xs [SXS * SXP];      // x tile; reused as v4 in phase 5/6
    __shared__ float hb [SXS * SHP];      // horiz conv of x; reused as v3
    __shared__ float hsq[SXS * SHP];      // horiz conv of x^2 (kept to end)
    __shared__ float mb [SM * SMP];       // mean field (kept to end)
    __shared__ float u3 [SM * SMP];       // xc^3
    __shared__ float u4 [SM * SMP];       // xc^4
    __shared__ float red[4][4];           // [feature][wave]

    // Gaussian weights (matches reference: fp32 exp, normalized)
    float g[K];
    {
        const float sigma = (float)K / 6.0f;
        const float inv2s2 = 1.0f / (2.0f * sigma * sigma);
        float s = 0.0f;
#pragma unroll
        for (int i = 0; i < K; ++i) {
            float c = (float)(i - K / 2);
            g[i] = expf(-c * c * inv2s2);
            s += g[i];
        }
#pragma unroll
        for (int i = 0; i < K; ++i) g[i] /= s;
    }

    const int bx    = blockIdx.x;
    const int plane = bx >> 8;            // 256 tiles per plane
    const int rem   = bx & 255;
    const int ty0   = (rem >> 4) * TILE;
    const int tx0   = (rem & 15) * TILE;
    const int tid   = threadIdx.x;

    const float* base_p = pred + (size_t)plane * H * W;
    const float* base_t = targ + (size_t)plane * H * W;

    float featp[TILE * TILE / NTHREADS][4];   // pred features, 4 px/thread
    float sum[4] = {0.f, 0.f, 0.f, 0.f};

    for (int t = 0; t < 2; ++t) {
        const float* __restrict__ src = (t == 0) ? base_p : base_t;

        __syncthreads();   // protect xs/hb reuse from previous tensor pass

        // Phase 1: load x tile with 2R halo, zero-padded
        for (int idx = tid; idx < SXS * SXS; idx += NTHREADS) {
            int r = idx / SXS, c = idx % SXS;
            int gy = ty0 - 2 * R + r, gx = tx0 - 2 * R + c;
            float v = 0.0f;
            if (gy >= 0 && gy < H && gx >= 0 && gx < W) v = src[gy * W + gx];
            xs[r * SXP + c] = v;
        }
        __syncthreads();

        // Phase 2: horizontal conv -> hb (x), hsq (x^2)
        for (int idx = tid; idx < SXS * SH; idx += NTHREADS) {
            int r = idx / SH, c = idx % SH;
            float a = 0.0f, b = 0.0f;
#pragma unroll
            for (int d = 0; d < K; ++d) {
                float x = xs[r * SXP + c + d];
                a += g[d] * x;
                b += g[d] * x * x;
            }
            hb [r * SHP + c] = a;
            hsq[r * SHP + c] = b;
        }
        __syncthreads();

        // Phase 3: vertical conv -> mean field over (TILE+2R)^2
        for (int idx = tid; idx < SM * SM; idx += NTHREADS) {
            int r = idx / SM, c = idx % SM;
            float a = 0.0f;
#pragma unroll
            for (int d = 0; d < K; ++d) a += g[d] * hb[(r + d) * SHP + c];
            mb[r * SMP + c] = a;
        }
        __syncthreads();

        // Phase 4: u3 = xc^3, u4 = xc^4 (zero outside image — conv pads the
        // xc FIELD with zeros, not (0 - mean))
        for (int idx = tid; idx < SM * SM; idx += NTHREADS) {
            int r = idx / SM, c = idx % SM;
            int gy = ty0 - R + r, gx = tx0 - R + c;
            float t3 = 0.0f, t4 = 0.0f;
            if (gy >= 0 && gy < H && gx >= 0 && gx < W) {
                float xc  = xs[(r + R) * SXP + (c + R)] - mb[r * SMP + c];
                float xc2 = xc * xc;
                t3 = xc2 * xc;
                t4 = xc2 * xc2;
            }
            u3[r * SMP + c] = t3;
            u4[r * SMP + c] = t4;
        }
        __syncthreads();

        // Phase 5: horizontal conv u3 -> v3 (into hb), u4 -> v4 (into xs)
        for (int idx = tid; idx < SM * TILE; idx += NTHREADS) {
            int r = idx / TILE, c = idx % TILE;
            float a = 0.0f, b = 0.0f;
#pragma unroll
            for (int d = 0; d < K; ++d) {
                a += g[d] * u3[r * SMP + c + d];
                b += g[d] * u4[r * SMP + c + d];
            }
            hb[r * TV + c] = a;   // v3
            xs[r * TV + c] = b;   // v4
        }
        __syncthreads();

        // Phase 6: per-center vertical convs + features
#pragma unroll
        for (int i = 0; i < TILE * TILE / NTHREADS; ++i) {
            int idx = tid + i * NTHREADS;
            int r = idx / TILE, c = idx % TILE;
            float mean = mb[(r + R) * SMP + (c + R)];
            float msq = 0.0f, m3 = 0.0f, m4 = 0.0f;
#pragma unroll
            for (int d = 0; d < K; ++d) {
                msq += g[d] * hsq[(r + R + d) * SHP + (c + R)];
                m3  += g[d] * hb [(r + d) * TV + c];
                m4  += g[d] * xs [(r + d) * TV + c];
            }
            float var  = fmaxf(msq - mean * mean, EPSF);
            float sd   = sqrtf(var);
            float skew = m3 / (sd * var + EPSF);        // std^3 = sd*var
            float kurt = m4 / (var * var + EPSF);
            if (t == 0) {
                featp[i][0] = mean; featp[i][1] = var;
                featp[i][2] = skew; featp[i][3] = kurt;
            } else {
                sum[0] += fabsf(featp[i][0] - mean);
                sum[1] += fabsf(featp[i][1] - var);
                sum[2] += fabsf(featp[i][2] - skew);
                sum[3] += fabsf(featp[i][3] - kurt);
            }
        }
    }

    // Block reduction: wave shuffle then cross-wave via LDS, 4 atomics/block
#pragma unroll
    for (int f = 0; f < 4; ++f) {
        float s = sum[f];
#pragma unroll
        for (int off = 32; off > 0; off >>= 1) s += __shfl_down(s, off, 64);
        if ((tid & 63) == 0) red[f][tid >> 6] = s;
    }
    __syncthreads();
    if (tid < 4) {
        float s = red[tid][0] + red[tid][1] + red[tid][2] + red[tid][3];
        atomicAdd(&acc[tid], (double)s);
    }
}

extern "C" void kernel_launch(void* const* d_in, const int* in_sizes, int n_in,
                              void* d_out, int out_size, void* d_ws, size_t ws_size,
                              hipStream_t stream) {
    const float* pred = (const float*)d_in[0];
    const float* targ = (const float*)d_in[1];
    double* acc = (double*)d_ws;
    float* out = (float*)d_out;

    init_acc_kernel<<<1, 64, 0, stream>>>(acc);

    dim3 grid(PLANES * (H / TILE) * (W / TILE));   // 48 * 256 = 12288 blocks
    stat_kernel<3><<<grid, NTHREADS, 0, stream>>>(pred, targ, acc);
    stat_kernel<5><<<grid, NTHREADS, 0, stream>>>(pred, targ, acc);
    stat_kernel<7><<<grid, NTHREADS, 0, stream>>>(pred, targ, acc);

    final_kernel<<<1, 64, 0, stream>>>(acc, out);
}

// Round 2
// 690.037 us; speedup vs baseline: 1.0755x; 1.0755x over previous
//
#include <hip/hip_runtime.h>
#include <math.h>

// StatisticalFeatureLoss: for k in {3,5,7}, gaussian-window local
// mean/var/skew/kurt of pred & target, scalar mean-abs-diff loss.
// R1: float4-vectorized phases — b128 LDS ops, 4x less addressing overhead.

#define NTHREADS 256
#define TILE 32

static constexpr int H = 512;
static constexpr int W = 512;
static constexpr int PLANES = 48;      // 16 * 3
static constexpr float EPSF = 1e-8f;

constexpr int round4(int x) { return (x + 3) & ~3; }
constexpr int pad_stride(int x) { int r = round4(x); return (r % 8 == 0) ? r + 4 : r; }

__global__ void init_acc_kernel(double* acc) {
    if (threadIdx.x < 4) acc[threadIdx.x] = 0.0;
}

__global__ void final_kernel(const double* __restrict__ acc, float* __restrict__ out) {
    if (threadIdx.x == 0) {
        const double npix = (double)PLANES * H * W;
        double tot = acc[0] + acc[1] + 0.5 * acc[2] + 0.001 * acc[3];
        out[0] = (float)(tot / (npix * 12.0));
    }
}

// Load Wd consecutive LDS floats starting at col (j0 + C), j0 % 4 == 0,
// via aligned float4 reads + compile-time register extracts.
template <int C, int Wd>
__device__ __forceinline__ void load_win(const float* __restrict__ rowbase, int j0,
                                         float* __restrict__ out) {
    constexpr int S = C & 3;
    constexpr int B = C - S;
    constexpr int NCH = (S + Wd + 3) / 4;
    float4 ch[NCH];
#pragma unroll
    for (int i = 0; i < NCH; ++i)
        ch[i] = *(const float4*)(rowbase + j0 + B + 4 * i);
    const float* f = reinterpret_cast<const float*>(ch);
#pragma unroll
    for (int t = 0; t < Wd; ++t) out[t] = f[S + t];
}

template <int K>
__global__ __launch_bounds__(NTHREADS)
void stat_kernel(const float* __restrict__ pred, const float* __restrict__ targ,
                 double* __restrict__ acc) {
    constexpr int R   = K / 2;
    constexpr int L   = (K == 7) ? 8 : 4;           // left halo: 4-aligned, >= 2R
    constexpr int XR  = TILE + 4 * R;               // x tile rows (36/40/44)
    constexpr int XC  = round4(L + TILE + 2 * R);   // x tile stride (40/40/48)
    constexpr int XC4 = XC / 4;
    constexpr int HC  = TILE + 2 * R;               // field cols/rows (34/36/38)
    constexpr int MR  = HC;
    constexpr int SH  = pad_stride(HC);             // hb/mb stride (36/36/44)
    constexpr int NCHH = round4(HC) / 4;            // field col chunks (9/9/10)
    constexpr int UP  = 4 * NCHH;                   // u3/u4 stride (36/36/40)
    constexpr int TP  = pad_stride(TILE);           // 36: hsq_s/v3/v4 stride

    constexpr int XS_SZ = XR * XC;
    constexpr int HB_SZ = XR * SH;
    constexpr int HS_SZ = MR * TP;
    constexpr int MB_SZ = MR * SH;
    constexpr int U_SZ  = MR * UP;
    constexpr int V_SZ  = MR * TP;
    static_assert(V_SZ <= HB_SZ && V_SZ <= XS_SZ, "alias sizes");

    __shared__ float smem[XS_SZ + HB_SZ + HS_SZ + MB_SZ + 2 * U_SZ];
    __shared__ float red[4][4];
    float* const xs  = smem;            // x tile; aliased as v4 after P4
    float* const hb  = xs + XS_SZ;      // h-conv(x); aliased as v3 after P3
    float* const hsq = hb + HB_SZ;      // h-conv(x^2), pre-shifted by R in row+col
    float* const mb  = hsq + HS_SZ;     // mean field
    float* const u3  = mb + MB_SZ;      // xc^3
    float* const u4  = u3 + U_SZ;       // xc^4
    float* const v3  = hb;
    float* const v4  = xs;

    // Gaussian weights (matches reference numerics)
    float g[K];
    {
        const float sigma = (float)K / 6.0f;
        const float inv2s2 = 1.0f / (2.0f * sigma * sigma);
        float s = 0.0f;
#pragma unroll
        for (int i = 0; i < K; ++i) {
            float c = (float)(i - K / 2);
            g[i] = expf(-c * c * inv2s2);
            s += g[i];
        }
#pragma unroll
        for (int i = 0; i < K; ++i) g[i] /= s;
    }

    const int bx    = blockIdx.x;
    const int plane = bx >> 8;
    const int rem   = bx & 255;
    const int ty0   = (rem >> 4) * TILE;
    const int tx0   = (rem & 15) * TILE;
    const int tid   = threadIdx.x;

    const float* base_p = pred + (size_t)plane * H * W;
    const float* base_t = targ + (size_t)plane * H * W;

    float featp[4][4];                 // 4 px/thread x 4 features (pred)
    float sum[4] = {0.f, 0.f, 0.f, 0.f};

    for (int t = 0; t < 2; ++t) {
        const float* __restrict__ src = (t == 0) ? base_p : base_t;

        __syncthreads();   // protect xs/hb (v4/v3) reuse from previous pass

        // ---- P1: load x tile (f4 global loads, zero-padded) ----
        for (int it = tid; it < XR * XC4; it += NTHREADS) {
            int r  = it / XC4;
            int c4 = (it - r * XC4) * 4;
            int gy = ty0 - 2 * R + r;
            int gx = tx0 - L + c4;
            const float* rp = src + (long)gy * W;
            float4 v;
            if ((unsigned)gy < (unsigned)H && (unsigned)gx < (unsigned)(W - 3)) {
                v = *(const float4*)(rp + gx);
            } else {
                float* vf = (float*)&v;
#pragma unroll
                for (int e = 0; e < 4; ++e) {
                    int x = gx + e;
                    vf[e] = ((unsigned)gy < (unsigned)H && (unsigned)x < (unsigned)W)
                              ? rp[x] : 0.f;
                }
            }
            *(float4*)(xs + r * XC + c4) = v;
        }
        __syncthreads();

        // ---- P2a: horizontal conv of x -> hb (rows XR, cols 4*NCHH) ----
        for (int it = tid; it < XR * NCHH; it += NTHREADS) {
            int r  = it / NCHH;
            int j0 = (it - r * NCHH) * 4;
            float w[K + 3];
            load_win<L - 2 * R, K + 3>(xs + r * XC, j0, w);
            float a[4];
#pragma unroll
            for (int e = 0; e < 4; ++e) {
                float s = 0.f;
#pragma unroll
                for (int d = 0; d < K; ++d) s += g[d] * w[e + d];
                a[e] = s;
            }
            *(float4*)(hb + r * SH + j0) = make_float4(a[0], a[1], a[2], a[3]);
        }

        // ---- P2b: horizontal conv of x^2 -> hsq_s (pre-shifted: rows MR, cols 32) ----
        for (int it = tid; it < MR * (TILE / 4); it += NTHREADS) {
            int r  = it / (TILE / 4);
            int j0 = (it - r * (TILE / 4)) * 4;
            float w[K + 3];
            load_win<L - R, K + 3>(xs + (r + R) * XC, j0, w);
            float a[4];
#pragma unroll
            for (int e = 0; e < 4; ++e) {
                float s = 0.f;
#pragma unroll
                for (int d = 0; d < K; ++d) s += g[d] * w[e + d] * w[e + d];
                a[e] = s;
            }
            *(float4*)(hsq + r * TP + j0) = make_float4(a[0], a[1], a[2], a[3]);
        }
        __syncthreads();

        // ---- P3: vertical conv hb -> mean field mb (MR x 4*NCHH) ----
        for (int it = tid; it < MR * NCHH; it += NTHREADS) {
            int m  = it / NCHH;
            int j0 = (it - m * NCHH) * 4;
            float a[4] = {0.f, 0.f, 0.f, 0.f};
#pragma unroll
            for (int d = 0; d < K; ++d) {
                float4 h = *(const float4*)(hb + (m + d) * SH + j0);
                const float* hf = (const float*)&h;
#pragma unroll
                for (int e = 0; e < 4; ++e) a[e] += g[d] * hf[e];
            }
            *(float4*)(mb + m * SH + j0) = make_float4(a[0], a[1], a[2], a[3]);
        }
        __syncthreads();

        // ---- P4: u3 = xc^3, u4 = xc^4 (zero outside image) ----
        for (int it = tid; it < MR * NCHH; it += NTHREADS) {
            int m  = it / NCHH;
            int j0 = (it - m * NCHH) * 4;
            float xw[4];
            load_win<L - R, 4>(xs + (m + R) * XC, j0, xw);
            float4 mn4 = *(const float4*)(mb + m * SH + j0);
            const float* mn = (const float*)&mn4;
            int gy = ty0 - R + m;
            bool rowok = (unsigned)gy < (unsigned)H;
            float t3[4], t4[4];
#pragma unroll
            for (int e = 0; e < 4; ++e) {
                int gx = tx0 - R + j0 + e;
                bool ok = rowok && (unsigned)gx < (unsigned)W;
                float xc  = xw[e] - mn[e];
                float xc2 = xc * xc;
                t3[e] = ok ? xc2 * xc : 0.f;
                t4[e] = ok ? xc2 * xc2 : 0.f;
            }
            *(float4*)(u3 + m * UP + j0) = make_float4(t3[0], t3[1], t3[2], t3[3]);
            *(float4*)(u4 + m * UP + j0) = make_float4(t4[0], t4[1], t4[2], t4[3]);
        }
        __syncthreads();

        // ---- P5: horizontal conv u3 -> v3, u4 -> v4 (MR x 32) ----
        for (int it = tid; it < MR * (TILE / 4); it += NTHREADS) {
            int m  = it / (TILE / 4);
            int c0 = (it - m * (TILE / 4)) * 4;
            float w3[K + 3], w4[K + 3];
            load_win<0, K + 3>(u3 + m * UP, c0, w3);
            load_win<0, K + 3>(u4 + m * UP, c0, w4);
            float a3[4] = {0.f, 0.f, 0.f, 0.f}, a4[4] = {0.f, 0.f, 0.f, 0.f};
#pragma unroll
            for (int d = 0; d < K; ++d)
#pragma unroll
                for (int e = 0; e < 4; ++e) {
                    a3[e] += g[d] * w3[e + d];
                    a4[e] += g[d] * w4[e + d];
                }
            *(float4*)(v3 + m * TP + c0) = make_float4(a3[0], a3[1], a3[2], a3[3]);
            *(float4*)(v4 + m * TP + c0) = make_float4(a4[0], a4[1], a4[2], a4[3]);
        }
        __syncthreads();

        // ---- P6: per-center vertical convs + features (1 f4 chunk/thread) ----
        {
            int r  = tid >> 3;
            int c0 = (tid & 7) * 4;
            float mnw[4];
            load_win<R, 4>(mb + (r + R) * SH, c0, mnw);
            float msq[4] = {0.f, 0.f, 0.f, 0.f};
            float m3[4]  = {0.f, 0.f, 0.f, 0.f};
            float m4[4]  = {0.f, 0.f, 0.f, 0.f};
#pragma unroll
            for (int d = 0; d < K; ++d) {
                float4 hq = *(const float4*)(hsq + (r + d) * TP + c0);
                float4 b3 = *(const float4*)(v3  + (r + d) * TP + c0);
                float4 b4 = *(const float4*)(v4  + (r + d) * TP + c0);
                const float* hqf = (const float*)&hq;
                const float* b3f = (const float*)&b3;
                const float* b4f = (const float*)&b4;
#pragma unroll
                for (int e = 0; e < 4; ++e) {
                    msq[e] += g[d] * hqf[e];
                    m3[e]  += g[d] * b3f[e];
                    m4[e]  += g[d] * b4f[e];
                }
            }
#pragma unroll
            for (int e = 0; e < 4; ++e) {
                float mean = mnw[e];
                float var  = fmaxf(msq[e] - mean * mean, EPSF);
                float sd   = sqrtf(var);
                float skew = __fdividef(m3[e], sd * var + EPSF);
                float kurt = __fdividef(m4[e], var * var + EPSF);
                if (t == 0) {
                    featp[e][0] = mean; featp[e][1] = var;
                    featp[e][2] = skew; featp[e][3] = kurt;
                } else {
                    sum[0] += fabsf(featp[e][0] - mean);
                    sum[1] += fabsf(featp[e][1] - var);
                    sum[2] += fabsf(featp[e][2] - skew);
                    sum[3] += fabsf(featp[e][3] - kurt);
                }
            }
        }
    }

    // Block reduction: wave shuffle then cross-wave via LDS, 4 atomics/block
#pragma unroll
    for (int f = 0; f < 4; ++f) {
        float s = sum[f];
#pragma unroll
        for (int off = 32; off > 0; off >>= 1) s += __shfl_down(s, off, 64);
        if ((tid & 63) == 0) red[f][tid >> 6] = s;
    }
    __syncthreads();
    if (tid < 4) {
        float s = red[tid][0] + red[tid][1] + red[tid][2] + red[tid][3];
        atomicAdd(&acc[tid], (double)s);
    }
}

extern "C" void kernel_launch(void* const* d_in, const int* in_sizes, int n_in,
                              void* d_out, int out_size, void* d_ws, size_t ws_size,
                              hipStream_t stream) {
    const float* pred = (const float*)d_in[0];
    const float* targ = (const float*)d_in[1];
    double* acc = (double*)d_ws;
    float* out = (float*)d_out;

    init_acc_kernel<<<1, 64, 0, stream>>>(acc);

    dim3 grid(PLANES * (H / TILE) * (W / TILE));   // 12288 blocks
    stat_kernel<3><<<grid, NTHREADS, 0, stream>>>(pred, targ, acc);
    stat_kernel<5><<<grid, NTHREADS, 0, stream>>>(pred, targ, acc);
    stat_kernel<7><<<grid, NTHREADS, 0, stream>>>(pred, targ, acc);

    final_kernel<<<1, 64, 0, stream>>>(acc, out);
}